// Round 1
// baseline (737.143 us; speedup 1.0000x reference)
//
#include <hip/hip_runtime.h>

// Problem constants (fixed by setup_inputs in the reference)
#define B  16
#define C  64
#define IH 256
#define IW 256
#define OH 256
#define OW 256

// One block = one output row (b,h); threadIdx.x = w.
// Each thread computes sampling coords once, loops over channels.
__global__ __launch_bounds__(256) void ast_sample(const float* __restrict__ inp,
                                                  const float* __restrict__ theta,
                                                  float* __restrict__ out) {
    const int w = threadIdx.x;                 // 0..255
    const int h = blockIdx.x & (OH - 1);
    const int b = blockIdx.x >> 8;             // OH == 256

    // linspace(-1,1,N) with align_corners semantics
    const float wn = -1.0f + (2.0f / (float)(OW - 1)) * (float)w;
    const float hn = -1.0f + (2.0f / (float)(OH - 1)) * (float)h;

    const float t00 = theta[b * 6 + 0];
    const float t01 = theta[b * 6 + 1];
    const float t02 = theta[b * 6 + 2];
    const float t10 = theta[b * 6 + 3];
    const float t11 = theta[b * 6 + 4];
    const float t12 = theta[b * 6 + 5];

    const float gx = t00 * wn + t01 * hn + t02;
    const float gy = t10 * wn + t11 * hn + t12;

    const float ix = (gx + 1.0f) * ((float)(IW - 1) * 0.5f);
    const float iy = (gy + 1.0f) * ((float)(IH - 1) * 0.5f);

    const float x0f = floorf(ix);
    const float y0f = floorf(iy);
    const float x1f = x0f + 1.0f;
    const float y1f = y0f + 1.0f;

    const float wx1 = ix - x0f;
    const float wy1 = iy - y0f;
    const float wx0 = 1.0f - wx1;
    const float wy0 = 1.0f - wy1;

    const bool inx0 = (x0f >= 0.0f) && (x0f <= (float)(IW - 1));
    const bool inx1 = (x1f >= 0.0f) && (x1f <= (float)(IW - 1));
    const bool iny0 = (y0f >= 0.0f) && (y0f <= (float)(IH - 1));
    const bool iny1 = (y1f >= 0.0f) && (y1f <= (float)(IH - 1));

    const float w00 = (inx0 && iny0) ? wx0 * wy0 : 0.0f;
    const float w10 = (inx1 && iny0) ? wx1 * wy0 : 0.0f;
    const float w01 = (inx0 && iny1) ? wx0 * wy1 : 0.0f;
    const float w11 = (inx1 && iny1) ? wx1 * wy1 : 0.0f;

    const int x0 = (int)fminf(fmaxf(x0f, 0.0f), (float)(IW - 1));
    const int x1 = (int)fminf(fmaxf(x1f, 0.0f), (float)(IW - 1));
    const int y0 = (int)fminf(fmaxf(y0f, 0.0f), (float)(IH - 1));
    const int y1 = (int)fminf(fmaxf(y1f, 0.0f), (float)(IH - 1));

    const int off00 = y0 * IW + x0;
    const int off10 = y0 * IW + x1;
    const int off01 = y1 * IW + x0;
    const int off11 = y1 * IW + x1;

    const float* __restrict__ base = inp + (size_t)b * C * IH * IW;
    float* __restrict__ obase = out + (size_t)b * C * OH * OW + (size_t)h * OW + (size_t)w;

    // Entire 2x2 footprint outside the image -> pure zero output, no loads.
    const bool all_oob = (x1f < 0.0f) || (x0f > (float)(IW - 1)) ||
                         (y1f < 0.0f) || (y0f > (float)(IH - 1));

    if (all_oob) {
        #pragma unroll 8
        for (int c = 0; c < C; ++c) {
            obase[(size_t)c * (OH * OW)] = 0.0f;
        }
    } else {
        #pragma unroll 4
        for (int c = 0; c < C; ++c) {
            const float* __restrict__ p = base + (size_t)c * (IH * IW);
            float v = w00 * p[off00];
            v = fmaf(w10, p[off10], v);
            v = fmaf(w01, p[off01], v);
            v = fmaf(w11, p[off11], v);
            obase[(size_t)c * (OH * OW)] = v;
        }
    }
}

// VERTICES = [[-1,-1,1],[-1,1,1],[1,1,1],[1,-1,1]]
// vout[b,v,:] = theta[b] @ V[v]; x=(vx+1)*IW/2, y=(vy+1)*IH/2
__global__ __launch_bounds__(64) void ast_vertices(const float* __restrict__ theta,
                                                   float* __restrict__ vo) {
    const int tid = threadIdx.x;               // 0..63
    if (tid >= B * 4) return;
    const int b = tid >> 2;
    const int v = tid & 3;

    // vertex table
    const float vx_tab[4] = {-1.0f, -1.0f, 1.0f, 1.0f};
    const float vy_tab[4] = {-1.0f,  1.0f, 1.0f, -1.0f};
    const float Vx = vx_tab[v];
    const float Vy = vy_tab[v];

    const float t00 = theta[b * 6 + 0];
    const float t01 = theta[b * 6 + 1];
    const float t02 = theta[b * 6 + 2];
    const float t10 = theta[b * 6 + 3];
    const float t11 = theta[b * 6 + 4];
    const float t12 = theta[b * 6 + 5];

    const float ox = t00 * Vx + t01 * Vy + t02;
    const float oy = t10 * Vx + t11 * Vy + t12;

    const float xc = (ox + 1.0f) * ((float)IW * 0.5f);
    const float yc = (oy + 1.0f) * ((float)IH * 0.5f);

    vo[(size_t)b * 8 + (size_t)v * 2 + 0] = xc;
    vo[(size_t)b * 8 + (size_t)v * 2 + 1] = yc;
}

extern "C" void kernel_launch(void* const* d_in, const int* in_sizes, int n_in,
                              void* d_out, int out_size, void* d_ws, size_t ws_size,
                              hipStream_t stream) {
    const float* inp   = (const float*)d_in[0];
    const float* theta = (const float*)d_in[1];
    // d_in[2] = OH, d_in[3] = OW (device ints) -- fixed at 256 by setup_inputs.

    float* out = (float*)d_out;
    float* vo  = out + (size_t)B * C * OH * OW;   // vertices_out follows the image

    ast_sample<<<B * OH, 256, 0, stream>>>(inp, theta, out);
    ast_vertices<<<1, 64, 0, stream>>>(theta, vo);
}

// Round 2
// 498.236 us; speedup vs baseline: 1.4795x; 1.4795x over previous
//
#include <hip/hip_runtime.h>

// Problem constants (fixed by setup_inputs in the reference)
#define B  16
#define C  64
#define IH 256
#define IW 256
#define OH 256
#define OW 256

// Tiling: each block = 32x8 output tile x 16 channels.
#define TW 32
#define TH 8
#define CC 16              // channels per block
#define NWT (OW / TW)      // 8
#define NHT (OH / TH)      // 32
#define NCC (C / CC)       // 4

__global__ __launch_bounds__(256) void ast_fused(const float* __restrict__ inp,
                                                 const float* __restrict__ theta,
                                                 float* __restrict__ out) {
    // ---- vertex output folded into block 0 (tiny: 128 floats) ----
    if (blockIdx.x == 0 && threadIdx.x < B * 4) {
        const int tid = threadIdx.x;
        const int b = tid >> 2;
        const int v = tid & 3;
        const float vx_tab[4] = {-1.0f, -1.0f, 1.0f, 1.0f};
        const float vy_tab[4] = {-1.0f,  1.0f, 1.0f, -1.0f};
        const float Vx = vx_tab[v];
        const float Vy = vy_tab[v];
        const float ox = theta[b*6+0]*Vx + theta[b*6+1]*Vy + theta[b*6+2];
        const float oy = theta[b*6+3]*Vx + theta[b*6+4]*Vy + theta[b*6+5];
        float* vo = out + (size_t)B * C * OH * OW;
        vo[b*8 + v*2 + 0] = (ox + 1.0f) * ((float)IW * 0.5f);
        vo[b*8 + v*2 + 1] = (oy + 1.0f) * ((float)IH * 0.5f);
    }

    // ---- decode block -> (b, channel-chunk, h-tile, w-tile) ----
    int id = blockIdx.x;
    const int wt = id & (NWT - 1); id >>= 3;   // 8 w-tiles
    const int ht = id & (NHT - 1); id >>= 5;   // 32 h-tiles
    const int cc = id & (NCC - 1); id >>= 2;   // 4 channel chunks
    const int b  = id;                         // 16 batches

    const int tx = threadIdx.x & (TW - 1);
    const int ty = threadIdx.x >> 5;
    const int w = wt * TW + tx;
    const int h = ht * TH + ty;

    // linspace(-1,1,N), align_corners
    const float wn = -1.0f + (2.0f / (float)(OW - 1)) * (float)w;
    const float hn = -1.0f + (2.0f / (float)(OH - 1)) * (float)h;

    const float t00 = theta[b*6+0], t01 = theta[b*6+1], t02 = theta[b*6+2];
    const float t10 = theta[b*6+3], t11 = theta[b*6+4], t12 = theta[b*6+5];

    const float gx = t00 * wn + t01 * hn + t02;
    const float gy = t10 * wn + t11 * hn + t12;

    const float ix = (gx + 1.0f) * ((float)(IW - 1) * 0.5f);
    const float iy = (gy + 1.0f) * ((float)(IH - 1) * 0.5f);

    const float x0f = floorf(ix);
    const float y0f = floorf(iy);

    const float wx1 = ix - x0f;
    const float wy1 = iy - y0f;
    const float wx0 = 1.0f - wx1;
    const float wy0 = 1.0f - wy1;

    const bool inx0 = (x0f >= 0.0f) && (x0f <= (float)(IW - 1));
    const bool inx1 = (x0f + 1.0f >= 0.0f) && (x0f + 1.0f <= (float)(IW - 1));
    const bool iny0 = (y0f >= 0.0f) && (y0f <= (float)(IH - 1));
    const bool iny1 = (y0f + 1.0f >= 0.0f) && (y0f + 1.0f <= (float)(IH - 1));

    const float w00 = (inx0 && iny0) ? wx0 * wy0 : 0.0f;
    const float w10 = (inx1 && iny0) ? wx1 * wy0 : 0.0f;
    const float w01 = (inx0 && iny1) ? wx0 * wy1 : 0.0f;
    const float w11 = (inx1 && iny1) ? wx1 * wy1 : 0.0f;

    const int x0 = (int)fminf(fmaxf(x0f,        0.0f), (float)(IW - 1));
    const int x1 = (int)fminf(fmaxf(x0f + 1.0f, 0.0f), (float)(IW - 1));
    const int y0 = (int)fminf(fmaxf(y0f,        0.0f), (float)(IH - 1));
    const int y1 = (int)fminf(fmaxf(y0f + 1.0f, 0.0f), (float)(IH - 1));

    const int off00 = y0 * IW + x0;
    const int off10 = y0 * IW + x1;
    const int off01 = y1 * IW + x0;
    const int off11 = y1 * IW + x1;

    const bool any_in = (inx0 || inx1) && (iny0 || iny1);

    const int c0 = cc * CC;
    const float* __restrict__ p = inp + ((size_t)b * C + c0) * (IH * IW);
    float* __restrict__ o = out + (((size_t)b * C + c0) * OH + h) * OW + w;

    if (any_in) {
        #pragma unroll 8
        for (int c = 0; c < CC; ++c) {
            float v = w00 * p[off00];
            v = fmaf(w10, p[off10], v);
            v = fmaf(w01, p[off01], v);
            v = fmaf(w11, p[off11], v);
            __builtin_nontemporal_store(v, o);
            p += IH * IW;
            o += OH * OW;
        }
    } else {
        #pragma unroll 8
        for (int c = 0; c < CC; ++c) {
            __builtin_nontemporal_store(0.0f, o);
            o += OH * OW;
        }
    }
}

extern "C" void kernel_launch(void* const* d_in, const int* in_sizes, int n_in,
                              void* d_out, int out_size, void* d_ws, size_t ws_size,
                              hipStream_t stream) {
    const float* inp   = (const float*)d_in[0];
    const float* theta = (const float*)d_in[1];
    float* out = (float*)d_out;

    ast_fused<<<B * NCC * NHT * NWT, 256, 0, stream>>>(inp, theta, out);
}

// Round 3
// 467.275 us; speedup vs baseline: 1.5775x; 1.0663x over previous
//
#include <hip/hip_runtime.h>

// Problem constants (fixed by setup_inputs in the reference)
#define B  16
#define C  64
#define IH 256
#define IW 256
#define OH 256
#define OW 256

// Tiling: each block = 32x8 output tile x 16 channels.
#define TW 32
#define TH 8
#define CC 16              // channels per block
#define NWT (OW / TW)      // 8
#define NHT (OH / TH)      // 32
#define NCC (C / CC)       // 4

// float2 vector with only 4-byte alignment guarantee: lets the compiler emit
// a wide load on targets with unaligned-access support, or split safely.
typedef float f2 __attribute__((ext_vector_type(2)));
typedef f2 __attribute__((aligned(4))) f2u;

__global__ __launch_bounds__(256) void ast_fused(const float* __restrict__ inp,
                                                 const float* __restrict__ theta,
                                                 float* __restrict__ out) {
    // ---- vertex output folded into block 0 (tiny: 128 floats) ----
    if (blockIdx.x == 0 && threadIdx.x < B * 4) {
        const int tid = threadIdx.x;
        const int b = tid >> 2;
        const int v = tid & 3;
        const float vx_tab[4] = {-1.0f, -1.0f, 1.0f, 1.0f};
        const float vy_tab[4] = {-1.0f,  1.0f, 1.0f, -1.0f};
        const float Vx = vx_tab[v];
        const float Vy = vy_tab[v];
        const float ox = theta[b*6+0]*Vx + theta[b*6+1]*Vy + theta[b*6+2];
        const float oy = theta[b*6+3]*Vx + theta[b*6+4]*Vy + theta[b*6+5];
        float* vo = out + (size_t)B * C * OH * OW;
        vo[b*8 + v*2 + 0] = (ox + 1.0f) * ((float)IW * 0.5f);
        vo[b*8 + v*2 + 1] = (oy + 1.0f) * ((float)IH * 0.5f);
    }

    // ---- decode block -> (b, channel-chunk, h-tile, w-tile) ----
    int id = blockIdx.x;
    const int wt = id & (NWT - 1); id >>= 3;   // 8 w-tiles
    const int ht = id & (NHT - 1); id >>= 5;   // 32 h-tiles
    const int cc = id & (NCC - 1); id >>= 2;   // 4 channel chunks
    const int b  = id;                         // 16 batches

    const int tx = threadIdx.x & (TW - 1);
    const int ty = threadIdx.x >> 5;
    const int w = wt * TW + tx;
    const int h = ht * TH + ty;

    // linspace(-1,1,N), align_corners
    const float wn = -1.0f + (2.0f / (float)(OW - 1)) * (float)w;
    const float hn = -1.0f + (2.0f / (float)(OH - 1)) * (float)h;

    const float t00 = theta[b*6+0], t01 = theta[b*6+1], t02 = theta[b*6+2];
    const float t10 = theta[b*6+3], t11 = theta[b*6+4], t12 = theta[b*6+5];

    const float gx = t00 * wn + t01 * hn + t02;
    const float gy = t10 * wn + t11 * hn + t12;

    const float ix = (gx + 1.0f) * ((float)(IW - 1) * 0.5f);
    const float iy = (gy + 1.0f) * ((float)(IH - 1) * 0.5f);

    const float x0f = floorf(ix);
    const float y0f = floorf(iy);

    const float wx1 = ix - x0f;
    const float wy1 = iy - y0f;
    const float wx0 = 1.0f - wx1;
    const float wy0 = 1.0f - wy1;

    const bool inx0 = (x0f >= 0.0f) && (x0f <= (float)(IW - 1));
    const bool inx1 = (x0f + 1.0f >= 0.0f) && (x0f + 1.0f <= (float)(IW - 1));
    const bool iny0 = (y0f >= 0.0f) && (y0f <= (float)(IH - 1));
    const bool iny1 = (y0f + 1.0f >= 0.0f) && (y0f + 1.0f <= (float)(IH - 1));

    const float w00 = (inx0 && iny0) ? wx0 * wy0 : 0.0f;
    const float w10 = (inx1 && iny0) ? wx1 * wy0 : 0.0f;
    const float w01 = (inx0 && iny1) ? wx0 * wy1 : 0.0f;
    const float w11 = (inx1 && iny1) ? wx1 * wy1 : 0.0f;

    // Paired-corner base x: pair covers (basex, basex+1); selects below pick
    // the right element for each corner (wrong element only where weight==0).
    const int  basex = (int)fminf(fmaxf(x0f, 0.0f), (float)(IW - 2));
    const bool selA  = (x0f <= (float)(IW - 2));   // corner x0 = pair.x
    const bool selB  = (x0f >= 0.0f);              // corner x1 = pair.y

    const int y0 = (int)fminf(fmaxf(y0f,        0.0f), (float)(IH - 1));
    const int y1 = (int)fminf(fmaxf(y0f + 1.0f, 0.0f), (float)(IH - 1));

    const int off0 = y0 * IW + basex;   // row y0: (x0c, x0c+1)
    const int off1 = y1 * IW + basex;   // row y1: (x0c, x0c+1)

    const bool any_in = (inx0 || inx1) && (iny0 || iny1);

    const int c0 = cc * CC;
    const float* __restrict__ p = inp + ((size_t)b * C + c0) * (IH * IW);
    float* __restrict__ o = out + (((size_t)b * C + c0) * OH + h) * OW + w;

    if (any_in) {
        #pragma unroll 16
        for (int c = 0; c < CC; ++c) {
            const f2 ra = *(const f2u*)(p + off0);
            const f2 rb = *(const f2u*)(p + off1);
            const float a00 = selA ? ra.x : ra.y;
            const float a10 = selB ? ra.y : ra.x;
            const float b00 = selA ? rb.x : rb.y;
            const float b11 = selB ? rb.y : rb.x;
            float v = w00 * a00;
            v = fmaf(w10, a10, v);
            v = fmaf(w01, b00, v);
            v = fmaf(w11, b11, v);
            __builtin_nontemporal_store(v, o);
            p += IH * IW;
            o += OH * OW;
        }
    } else {
        #pragma unroll 16
        for (int c = 0; c < CC; ++c) {
            __builtin_nontemporal_store(0.0f, o);
            o += OH * OW;
        }
    }
}

extern "C" void kernel_launch(void* const* d_in, const int* in_sizes, int n_in,
                              void* d_out, int out_size, void* d_ws, size_t ws_size,
                              hipStream_t stream) {
    const float* inp   = (const float*)d_in[0];
    const float* theta = (const float*)d_in[1];
    float* out = (float*)d_out;

    ast_fused<<<B * NCC * NHT * NWT, 256, 0, stream>>>(inp, theta, out);
}